// Round 9
// baseline (784.887 us; speedup 1.0000x reference)
//
#include <hip/hip_runtime.h>
#include <cstdint>
#include <cstddef>

#define N_NODES 100000
#define N_EDGES 3200000
#define DD 256
#define KK 512            // concatenated K: [emb+nb | nb*emb]
#define MPAD 100096       // 782 * 128
#define NSCAN 98          // ceil(N_NODES / 1024)
#define NGRP 8            // row-groups (== XCDs, heuristic)
#define GRP_ROWS 12500    // N_NODES / NGRP
#define SEGCAP 53248      // per-(grp,xcd) bucket segment capacity (~50K + 15 sigma)

typedef __attribute__((ext_vector_type(8))) __bf16 bf16x8;
typedef __attribute__((ext_vector_type(4))) __bf16 bf16x4;
typedef __attribute__((ext_vector_type(4))) float f32x4;

__device__ __forceinline__ void gload_lds16(const void* gsrc, void* lds) {
  __builtin_amdgcn_global_load_lds((const __attribute__((address_space(1))) void*)gsrc,
                                   (__attribute__((address_space(3))) void*)lds,
                                   16, 0, 0);
}

// ---------------- converts ----------------

__global__ void conve_kernel(const float* __restrict__ emb, __bf16* __restrict__ embB) {
  int i = blockIdx.x * blockDim.x + threadIdx.x;   // quad index, N*64 total
  float4 v = ((const float4*)emb)[i];
  bf16x4 o;
  o[0] = (__bf16)v.x; o[1] = (__bf16)v.y; o[2] = (__bf16)v.z; o[3] = (__bf16)v.w;
  ((bf16x4*)embB)[i] = o;
}

// Wt[n][k] = (k<256 ? W1[k][n] : W2[k-256][n]) as bf16, row-major [256][512]
__global__ void convw_kernel(const float* __restrict__ W1, const float* __restrict__ W2,
                             __bf16* __restrict__ Wt) {
  int idx = blockIdx.x * blockDim.x + threadIdx.x; // 0..131071 ; idx = n*512 + k
  int n = idx >> 9;
  int k = idx & 511;
  float v = (k < 256) ? W1[k * 256 + n] : W2[(k - 256) * 256 + n];
  Wt[idx] = (__bf16)v;
}

// ---------------- CSR build (single-pass bucketize) ----------------

__global__ void zero_ints_kernel(int* __restrict__ p, int n) {
  int i = blockIdx.x * blockDim.x + threadIdx.x;
  if (i < n) p[i] = 0;
}

// One streaming pass over edges. LDS-staged binning into 64 (grp,xcd) segments:
// push edge into 8-way LDS buffer by row-group, flush per 256-edge tile with
// ONE XCD-local atomic per (block,tile,group) and wave-cooperative contiguous
// writes. Replaces the 8-sweep hist/bin structure (8x102MB reads -> 38MB).
__global__ __launch_bounds__(256) void bucketize_kernel(
    const int* __restrict__ rows, const int* __restrict__ cols, const float* __restrict__ vals,
    int* __restrict__ gcur, uint32_t* __restrict__ br, uint32_t* __restrict__ bc,
    float* __restrict__ bv) {
  __shared__ int s_cnt[8];
  __shared__ int s_base[8];
  __shared__ uint32_t s_r[8][256];
  __shared__ uint32_t s_c[8][256];
  __shared__ float s_v[8][256];
  const int tid = threadIdx.x;
  const int x = blockIdx.x & 7;                    // XCD heuristic (perf-only)
  if (tid < 8) s_cnt[tid] = 0;
  __syncthreads();
  for (int e0 = blockIdx.x * 256; e0 < N_EDGES; e0 += gridDim.x * 256) {
    const int i = e0 + tid;
    if (i < N_EDGES) {
      const int r = rows[i];
      const int g = r / GRP_ROWS;                  // 0..7
      const int idx = atomicAdd(&s_cnt[g], 1);     // unique slot, <=256 per tile
      s_r[g][idx] = (uint32_t)r;
      s_c[g][idx] = (uint32_t)cols[i];
      s_v[g][idx] = vals[i];
    }
    __syncthreads();
    if (tid < 8) s_base[tid] = atomicAdd(&gcur[x * 16 + tid], s_cnt[tid]);
    __syncthreads();
#pragma unroll
    for (int g = 0; g < 8; ++g) {
      const int cnt = s_cnt[g];
      const size_t dst0 = (size_t)(g * 8 + x) * SEGCAP + s_base[g];
      for (int k = tid; k < cnt; k += 256) {
        br[dst0 + k] = s_r[g][k];
        bc[dst0 + k] = s_c[g][k];
        bv[dst0 + k] = s_v[g][k];
      }
    }
    __syncthreads();
    if (tid < 8) s_cnt[tid] = 0;
    __syncthreads();
  }
}

// Per-group histogram from bucket rows: block b -> (g=b&7, x, chunk).
// counts atomics XCD-local; reads 13.6MB sequential.
__global__ void histg_kernel(const uint32_t* __restrict__ br, const int* __restrict__ gcur,
                             int* __restrict__ counts) {
  const int g = blockIdx.x & 7;
  const int s = blockIdx.x >> 3;                   // 0..255
  const int x = s & 7;
  const int c = s >> 3;                            // 0..31
  const int len = gcur[x * 16 + g];
  const int cl = (len + 31) >> 5;
  const int lo = c * cl;
  const int hi = (lo + cl < len) ? lo + cl : len;
  const uint32_t* p = br + (size_t)(g * 8 + x) * SEGCAP;
  for (int i = lo + threadIdx.x; i < hi; i += 256) atomicAdd(&counts[p[i]], 1);
}

__global__ void scan_block_kernel(const int* __restrict__ counts, int* __restrict__ offsets,
                                  int* __restrict__ blockSums, int n) {
  __shared__ int s[1024];
  int t = threadIdx.x;
  int i = blockIdx.x * 1024 + t;
  int v = (i < n) ? counts[i] : 0;
  s[t] = v;
  __syncthreads();
  for (int off = 1; off < 1024; off <<= 1) {
    int x = (t >= off) ? s[t - off] : 0;
    __syncthreads();
    s[t] += x;
    __syncthreads();
  }
  if (i < n) offsets[i + 1] = s[t];       // block-local inclusive scan (base added later)
  if (t == 1023) blockSums[blockIdx.x] = s[1023];
}

__global__ void scan_sums_kernel(const int* __restrict__ blockSums, int* __restrict__ blockBase,
                                 int nb, int* __restrict__ offsets) {
  __shared__ int s[128];
  int t = threadIdx.x;          // launched with 128 threads, nb <= 128
  int v = (t < nb) ? blockSums[t] : 0;
  s[t] = v;
  __syncthreads();
  for (int off = 1; off < 128; off <<= 1) {
    int x = (t >= off) ? s[t - off] : 0;
    __syncthreads();
    s[t] += x;
    __syncthreads();
  }
  if (t < nb) blockBase[t] = s[t] - v;    // exclusive
  if (t == 0) offsets[0] = 0;
}

__global__ void scan_add_kernel(const int* __restrict__ counts, int* __restrict__ offsets,
                                const int* __restrict__ blockBase, int* __restrict__ cursor, int n) {
  int i = blockIdx.x * 1024 + threadIdx.x;
  if (i < n) {
    int incl = offsets[i + 1] + blockBase[blockIdx.x];
    offsets[i + 1] = incl;
    cursor[i] = incl - counts[i];         // exclusive prefix = row start
  }
}

// Within-group row-sort: block b -> (g=b&7, x, chunk); reads its group's
// segments sequentially, scatters into group-g sedge region (XCD-local
// cursor atomics + XCD-local data lines).
__global__ void bin2_kernel(const uint32_t* __restrict__ br, const uint32_t* __restrict__ bc,
                            const float* __restrict__ bv, const int* __restrict__ gcur,
                            int* __restrict__ cursor, uint2* __restrict__ sedge) {
  const int g = blockIdx.x & 7;
  const int s = blockIdx.x >> 3;
  const int x = s & 7;
  const int c = s >> 3;
  const int len = gcur[x * 16 + g];
  const int cl = (len + 31) >> 5;
  const int lo = c * cl;
  const int hi = (lo + cl < len) ? lo + cl : len;
  const size_t seg = (size_t)(g * 8 + x) * SEGCAP;
  for (int i = lo + threadIdx.x; i < hi; i += 256) {
    const int r = (int)br[seg + i];
    const int pos = atomicAdd(&cursor[r], 1);
    sedge[pos] = make_uint2(bc[seg + i], __float_as_uint(bv[seg + i]));
  }
}

// ---------------- fused SpMM: one wave per row, unroll 8 ----------------
// X[r][0:256]   = bf16(emb[r] + nb[r])
// X[r][256:512] = bf16(emb[r] * nb[r])

__global__ void spmm_fuse_kernel(const __bf16* __restrict__ embB, const int* __restrict__ offsets,
                                 const uint2* __restrict__ sedge, __bf16* __restrict__ X) {
  int gw = (blockIdx.x << 2) + (threadIdx.x >> 6);  // 4 waves / 256-thread block
  int lane = threadIdx.x & 63;
  bf16x4* xp1 = (bf16x4*)(X + (size_t)gw * KK + 4 * lane);
  bf16x4* xp2 = (bf16x4*)(X + (size_t)gw * KK + DD + 4 * lane);
  if (gw >= N_NODES) {                              // pad rows -> zeros
    bf16x4 z;
    z[0] = (__bf16)0.f; z[1] = (__bf16)0.f; z[2] = (__bf16)0.f; z[3] = (__bf16)0.f;
    *xp1 = z; *xp2 = z;
    return;
  }
  const bf16x4* ev = (const bf16x4*)embB;           // ev[c*64 + lane] = emb[c][4l..4l+3]
  float ax = 0.f, ay = 0.f, az = 0.f, aw = 0.f;
  int e = offsets[gw];
  const int eend = offsets[gw + 1];
  // unroll x8: 8 gathers in flight
  for (; e + 7 < eend; e += 8) {
    uint2 ee[8];
    bf16x4 xx[8];
#pragma unroll
    for (int u = 0; u < 8; ++u) ee[u] = sedge[e + u];
#pragma unroll
    for (int u = 0; u < 8; ++u) xx[u] = ev[(size_t)ee[u].x * 64 + lane];
#pragma unroll
    for (int u = 0; u < 8; ++u) {
      float v = __uint_as_float(ee[u].y);
      ax = fmaf(v, (float)xx[u][0], ax); ay = fmaf(v, (float)xx[u][1], ay);
      az = fmaf(v, (float)xx[u][2], az); aw = fmaf(v, (float)xx[u][3], aw);
    }
  }
  for (; e + 3 < eend; e += 4) {
    uint2 ee[4];
    bf16x4 xx[4];
#pragma unroll
    for (int u = 0; u < 4; ++u) ee[u] = sedge[e + u];
#pragma unroll
    for (int u = 0; u < 4; ++u) xx[u] = ev[(size_t)ee[u].x * 64 + lane];
#pragma unroll
    for (int u = 0; u < 4; ++u) {
      float v = __uint_as_float(ee[u].y);
      ax = fmaf(v, (float)xx[u][0], ax); ay = fmaf(v, (float)xx[u][1], ay);
      az = fmaf(v, (float)xx[u][2], az); aw = fmaf(v, (float)xx[u][3], aw);
    }
  }
  for (; e < eend; ++e) {
    uint2 ee = sedge[e];
    float v = __uint_as_float(ee.y);
    bf16x4 x = ev[(size_t)ee.x * 64 + lane];
    ax = fmaf(v, (float)x[0], ax); ay = fmaf(v, (float)x[1], ay);
    az = fmaf(v, (float)x[2], az); aw = fmaf(v, (float)x[3], aw);
  }
  bf16x4 er = ev[(size_t)gw * 64 + lane];
  float ex = (float)er[0], ey = (float)er[1], ez = (float)er[2], ew = (float)er[3];
  bf16x4 o1, o2;
  o1[0] = (__bf16)(ex + ax); o1[1] = (__bf16)(ey + ay);
  o1[2] = (__bf16)(ez + az); o1[3] = (__bf16)(ew + aw);
  o2[0] = (__bf16)(ex * ax); o2[1] = (__bf16)(ey * ay);
  o2[2] = (__bf16)(ez * az); o2[3] = (__bf16)(ew * aw);
  *xp1 = o1;
  *xp2 = o2;
}

// ---------------- GEMM: out[M=100000, N=256] = X[M,512] @ Wt^T ----------------
// m97-style 128x128 tile, BK=64, 4 waves. T2 LDS swizzle (rule #21): linear
// global_load_lds DEST + inverse-swizzled global SOURCE (chunk = lcol^lrow)
// + XOR-swizzled ds_read (byte ^= (row&7)<<4).

__global__ __launch_bounds__(256) void gemm_kernel(const __bf16* __restrict__ X,
                                                   const __bf16* __restrict__ Wt,
                                                   float* __restrict__ out) {
  __shared__ __align__(16) __bf16 As[128 * 64];   // [m][k], 128B rows, swizzled content
  __shared__ __align__(16) __bf16 Bs[128 * 64];   // [n][k]
  const int t = threadIdx.x;
  const int w = t >> 6, lane = t & 63;
  const int m0 = blockIdx.x * 128;
  const int n0 = blockIdx.y * 128;
  const int wm = (w >> 1) * 64, wn = (w & 1) * 64;
  const int lrow = lane >> 3, lcol = lane & 7;    // staging: 8 rows x 8 chunks per wave-instr
  const int scol = (lcol ^ lrow) * 8;             // inverse-swizzled source k-offset

  f32x4 acc[4][4];
#pragma unroll
  for (int i = 0; i < 4; ++i)
#pragma unroll
    for (int j = 0; j < 4; ++j) {
      f32x4 z = {0.f, 0.f, 0.f, 0.f};
      acc[i][j] = z;
    }

  for (int kt = 0; kt < KK; kt += 64) {
#pragma unroll
    for (int q = 0; q < 4; ++q) {
      const int cbase = w * 256 + q * 64;         // chunk base (16B chunks), HW adds +lane*16
      const int arow = m0 + w * 32 + q * 8 + lrow;
      gload_lds16(X + (size_t)arow * KK + kt + scol, (char*)As + cbase * 16);
      const int brow = n0 + w * 32 + q * 8 + lrow;
      gload_lds16(Wt + (size_t)brow * KK + kt + scol, (char*)Bs + cbase * 16);
    }
    __syncthreads();
    const int l15 = lane & 15, lhi = lane >> 4;
#pragma unroll
    for (int kk = 0; kk < 64; kk += 32) {
      bf16x8 af[4], bg[4];
#pragma unroll
      for (int i = 0; i < 4; ++i) {
        const int ar = wm + i * 16 + l15;
        af[i] = *(const bf16x8*)((const char*)As + ar * 128 +
                                 (((kk + lhi * 8) * 2) ^ ((ar & 7) << 4)));
      }
#pragma unroll
      for (int j = 0; j < 4; ++j) {
        const int br = wn + j * 16 + l15;
        bg[j] = *(const bf16x8*)((const char*)Bs + br * 128 +
                                 (((kk + lhi * 8) * 2) ^ ((br & 7) << 4)));
      }
#pragma unroll
      for (int i = 0; i < 4; ++i)
#pragma unroll
        for (int j = 0; j < 4; ++j)
          acc[i][j] = __builtin_amdgcn_mfma_f32_16x16x32_bf16(af[i], bg[j], acc[i][j], 0, 0, 0);
    }
    __syncthreads();
  }

  const int orow0 = m0 + wm + ((lane >> 4) << 2);
  const int ocol0 = n0 + wn + (lane & 15);
#pragma unroll
  for (int i = 0; i < 4; ++i)
#pragma unroll
    for (int j = 0; j < 4; ++j)
#pragma unroll
      for (int r = 0; r < 4; ++r) {
        const int row = orow0 + i * 16 + r;
        if (row < N_NODES) out[(size_t)row * DD + ocol0 + j * 16] = acc[i][j][r];
      }
}

// ---------------- launch ----------------

extern "C" void kernel_launch(void* const* d_in, const int* in_sizes, int n_in,
                              void* d_out, int out_size, void* d_ws, size_t ws_size,
                              hipStream_t stream) {
  const float* emb  = (const float*)d_in[0];
  const float* ev   = (const float*)d_in[1];
  const float* W1   = (const float*)d_in[2];
  const float* W2   = (const float*)d_in[3];
  const int* erows  = (const int*)d_in[4];
  const int* ecols  = (const int*)d_in[5];
  float* out = (float*)d_out;
  char* ws = (char*)d_ws;

  // workspace layout (~181 MB, proven). Buckets overlap the X region:
  // bin2 finishes with them before spmm writes X.
  const size_t OFF_X   = 0;                                    // MPAD*512*2   = 102,498,304
  const size_t OFF_BR  = OFF_X;                                // 64*SEGCAP*4 = 13,631,488
  const size_t OFF_BC  = OFF_BR + (size_t)64 * SEGCAP * 4;
  const size_t OFF_BV  = OFF_BC + (size_t)64 * SEGCAP * 4;     // ends at 40.9 MB < 102.5 MB
  const size_t OFF_EMB = OFF_X   + (size_t)MPAD * KK * 2;      // N*256*2     = 51,200,000
  const size_t OFF_WT  = OFF_EMB + (size_t)N_NODES * DD * 2;   // 512*256*2   = 262,144
  const size_t OFF_CNT = OFF_WT  + (size_t)KK * DD * 2;        // counts: 400,000 B
  const size_t OFF_GC  = OFF_CNT + 400000;                     // gcur: 128 ints (64B/XCD)
  const size_t OFF_OFS = OFF_CNT + 401408;
  const size_t OFF_CUR = OFF_OFS + 401408;
  const size_t OFF_BS  = OFF_CUR + 401408;
  const size_t OFF_BB  = OFF_BS  + 4096;
  const size_t OFF_SE  = OFF_BB  + 4096;                       // N_EDGES*8 packed (col,val)

  __bf16* X     = (__bf16*)(ws + OFF_X);
  uint32_t* br  = (uint32_t*)(ws + OFF_BR);
  uint32_t* bc  = (uint32_t*)(ws + OFF_BC);
  float* bv     = (float*)(ws + OFF_BV);
  __bf16* embB  = (__bf16*)(ws + OFF_EMB);
  __bf16* Wt    = (__bf16*)(ws + OFF_WT);
  int* counts   = (int*)(ws + OFF_CNT);
  int* gcur     = (int*)(ws + OFF_GC);
  int* offsets  = (int*)(ws + OFF_OFS);
  int* cursor   = (int*)(ws + OFF_CUR);
  int* bsums    = (int*)(ws + OFF_BS);
  int* bbase    = (int*)(ws + OFF_BB);
  uint2* sedge  = (uint2*)(ws + OFF_SE);

  // converts (independent)
  conve_kernel<<<(N_NODES * 64) / 256, 256, 0, stream>>>(emb, embB);
  convw_kernel<<<(KK * DD) / 256, 256, 0, stream>>>(W1, W2, Wt);

  // CSR build: zero counts+gcur, single-pass bucketize, per-group hist,
  // scan, within-group row-sort.
  zero_ints_kernel<<<(100128 + 255) / 256, 256, 0, stream>>>(counts, 100128);
  bucketize_kernel<<<2048, 256, 0, stream>>>(erows, ecols, ev, gcur, br, bc, bv);
  histg_kernel<<<2048, 256, 0, stream>>>(br, gcur, counts);
  scan_block_kernel<<<NSCAN, 1024, 0, stream>>>(counts, offsets, bsums, N_NODES);
  scan_sums_kernel<<<1, 128, 0, stream>>>(bsums, bbase, NSCAN, offsets);
  scan_add_kernel<<<NSCAN, 1024, 0, stream>>>(counts, offsets, bbase, cursor, N_NODES);
  bin2_kernel<<<2048, 256, 0, stream>>>(br, bc, bv, gcur, cursor, sedge);

  // fused SpMM -> X = [emb+nb | nb*emb] (bf16)
  spmm_fuse_kernel<<<MPAD / 4, 256, 0, stream>>>(embB, offsets, sedge, X);

  // single K=512 MFMA GEMM -> out
  gemm_kernel<<<dim3(MPAD / 128, 2), 256, 0, stream>>>(X, Wt, out);

  (void)in_sizes; (void)n_in; (void)out_size; (void)ws_size;
}